// Round 3
// baseline (161.826 us; speedup 1.0000x reference)
//
#include <hip/hip_runtime.h>
#include <hip/hip_bf16.h>
#include <math.h>

#define DEVFN __device__ __forceinline__

typedef __attribute__((ext_vector_type(8))) __bf16 bf16x8;
typedef __attribute__((ext_vector_type(8))) short s16x8;
typedef __attribute__((ext_vector_type(4))) float f32x4;
typedef __attribute__((ext_vector_type(4))) unsigned int u32x4;

constexpr int Tt    = 2048;
constexpr int INt   = 128;
constexpr int Ht    = 256;
constexpr int OUTt  = 8;
constexpr int TT    = 64;           // time tile
constexpr int NTILE = Tt / TT;      // 32

union Frag {
  s16x8 s;
  bf16x8 b;
  u32x4 u;
};

DEVFN unsigned short f2bf(float f) {
  unsigned int u = __builtin_bit_cast(unsigned int, f);
  u += 0x7fffu + ((u >> 16) & 1u);   // round-to-nearest-even
  return (unsigned short)(u >> 16);
}

DEVFN unsigned int pack2(float lo, float hi) {
  return (unsigned int)f2bf(lo) | ((unsigned int)f2bf(hi) << 16);
}

__global__ __launch_bounds__(1024, 4) void sfnn_fused(
    const float* __restrict__ x, const float* __restrict__ Wb,
    const float* __restrict__ bb, const float* __restrict__ Wo,
    const float* __restrict__ bo, const float* __restrict__ tau_m,
    const float* __restrict__ tau_n, float* __restrict__ out)
{
  const int b    = blockIdx.x;
  const int tid  = threadIdx.x;
  const int lane = tid & 63;
  const int w    = tid >> 6;          // wave id 0..15
  const int l16  = lane & 15;
  const int lhi  = lane >> 4;

  // D-GEMM wave geometry: 64t x 256h tile, each wave a 32x32 patch
  const int tg = w >> 3;              // rows [32tg, 32tg+32)
  const int hg = w & 7;               // cols [32hg, 32hg+32)
  // projection wave geometry: wave = 16t rows x 64-wide k slice
  const int tp = w >> 2;
  const int hp = w & 3;

  __shared__ __align__(16) unsigned char Xb[2][TT * INt * 2];   // bf16, swizzled
  __shared__ __align__(16) float          Df[TT * Ht];          // f32, swizzled
  __shared__ __align__(16) unsigned char  Mb[TT * Ht * 2];      // bf16, swizzled
  __shared__ float Plds[4][4][16][16];                          // [tp][hp][t16][j]

  // per-channel scan params (threads 0..255: channel = tid)
  const int   hch   = tid & 255;
  const float beta  = 1.f / (1.f + expf(-tau_n[hch]));
  const float alpha = 1.f / (1.f + expf(-tau_m[hch]));
  const float omb   = 1.f - beta;
  const float oma   = 1.f - alpha;
  const float bbh   = bb[hch];
  const float bo_j  = bo[tid & 7];

  // ---- branch-weight fragments (B operand of D-GEMM), registers all kernel ----
  Frag Wf[2][4];                      // [16-col half][k-step]
  #pragma unroll
  for (int nh = 0; nh < 2; ++nh) {
    const int h = 32 * hg + 16 * nh + l16;
    const int n = h >> 6, s = h & 63;
    #pragma unroll
    for (int ks = 0; ks < 4; ++ks) {
      #pragma unroll
      for (int j = 0; j < 8; ++j) {
        const int i = 32 * ks + 8 * lhi + j;
        Wf[nh][ks].s[j] = (short)f2bf(Wb[(n * 128 + i) * 64 + s]);
      }
    }
  }
  // ---- output-weight fragments (B operand of projection, cols >=8 zero) ----
  Frag WoF[2];
  #pragma unroll
  for (int ks = 0; ks < 2; ++ks) {
    #pragma unroll
    for (int j = 0; j < 8; ++j) {
      const int kk = 64 * hp + 32 * ks + 8 * lhi + j;
      const float v = (l16 < OUTt) ? Wo[kk * OUTt + l16] : 0.f;
      WoF[ks].s[j] = (short)f2bf(v);
    }
  }

  const float* xb   = x   + (size_t)b * Tt * INt;
  float*       outb = out + (size_t)b * Tt * OUTt;

  float c_s = 0.f, m_s = 0.f;

  // ---------------- helpers as macros over local state ----------------
  // issue: 2 fully-coalesced float4 loads (lane-contiguous 16KB per instr)
  #define ISSUE(TILE, Q0, Q1) do {                                         \
    const float* _s = xb + (size_t)(TILE) * (TT * INt);                    \
    Q0 = *(const float4*)(_s + 4 * (0 * 1024 + tid));                      \
    Q1 = *(const float4*)(_s + 4 * (1 * 1024 + tid));                      \
  } while (0)

  // stage: pack 2 float4 -> 2x b64 LDS writes (swizzled)
  #define STAGE(BUF, Q0, Q1) do {                                          \
    {                                                                      \
      const int R = 0 * 32 + (tid >> 5);                                   \
      const int bc = 8 * (tid & 31);                                       \
      unsigned long long pk = (unsigned long long)pack2(Q0.x, Q0.y) |      \
            ((unsigned long long)pack2(Q0.z, Q0.w) << 32);                 \
      *(unsigned long long*)(&Xb[BUF][R * 256 + (bc ^ ((R & 7) << 4))]) = pk; \
    }                                                                      \
    {                                                                      \
      const int R = 1 * 32 + (tid >> 5);                                   \
      const int bc = 8 * (tid & 31);                                       \
      unsigned long long pk = (unsigned long long)pack2(Q1.x, Q1.y) |      \
            ((unsigned long long)pack2(Q1.z, Q1.w) << 32);                 \
      *(unsigned long long*)(&Xb[BUF][R * 256 + (bc ^ ((R & 7) << 4))]) = pk; \
    }                                                                      \
  } while (0)

  #define GEMM(BUF, DACC) do {                                             \
    _Pragma("unroll")                                                      \
    for (int th = 0; th < 2; ++th) {                                       \
      const int row = 32 * tg + 16 * th + l16;                             \
      const int rs = row * 256, sw = (row & 7) << 4;                       \
      _Pragma("unroll")                                                    \
      for (int ks = 0; ks < 4; ++ks) {                                     \
        Frag a;                                                            \
        a.u = *(const u32x4*)(&Xb[BUF][rs + ((64 * ks + 16 * lhi) ^ sw)]); \
        _Pragma("unroll")                                                  \
        for (int nh = 0; nh < 2; ++nh)                                     \
          DACC[th][nh] = __builtin_amdgcn_mfma_f32_16x16x32_bf16(          \
              a.b, Wf[nh][ks].b, DACC[th][nh], 0, 0, 0);                   \
      }                                                                    \
    }                                                                      \
  } while (0)

  #define WRITEDF(DACC) do {                                               \
    _Pragma("unroll")                                                      \
    for (int th = 0; th < 2; ++th)                                         \
      _Pragma("unroll")                                                    \
      for (int nh = 0; nh < 2; ++nh) {                                     \
        const int h = 32 * hg + 16 * nh + l16;                             \
        _Pragma("unroll")                                                  \
        for (int r = 0; r < 4; ++r) {                                      \
          const int t = 32 * tg + 16 * th + 4 * lhi + r;                   \
          Df[t * 256 + (h ^ (((t >> 2) & 3) << 4))] = DACC[th][nh][r];     \
        }                                                                  \
      }                                                                    \
  } while (0)

  #define SCAN() do {                                                      \
    if (tid < 256) {                                                       \
      _Pragma("unroll")                                                    \
      for (int t = 0; t < TT; ++t) {                                       \
        const float d = Df[t * 256 + (tid ^ (((t >> 2) & 3) << 4))] + bbh; \
        c_s = fmaf(beta, c_s, omb * d);                                    \
        m_s = fmaf(alpha, m_s, oma * c_s);                                 \
        *(unsigned short*)(&Mb[(t * 256 + (tid ^ ((t & 7) << 3))) * 2]) = f2bf(m_s); \
      }                                                                    \
    }                                                                      \
  } while (0)

  #define PROJ() do {                                                      \
    f32x4 p = f32x4{0.f, 0.f, 0.f, 0.f};                                   \
    const int trow = 16 * tp + l16;                                        \
    _Pragma("unroll")                                                      \
    for (int ks = 0; ks < 2; ++ks) {                                       \
      const int h0 = 64 * hp + 32 * ks + 8 * lhi;                          \
      Frag ma;                                                             \
      ma.u = *(const u32x4*)(&Mb[(trow * 256 + (h0 ^ ((trow & 7) << 3))) * 2]); \
      p = __builtin_amdgcn_mfma_f32_16x16x32_bf16(ma.b, WoF[ks].b, p, 0, 0, 0); \
    }                                                                      \
    _Pragma("unroll")                                                      \
    for (int r = 0; r < 4; ++r)                                            \
      Plds[tp][hp][4 * lhi + r][l16] = p[r];                               \
  } while (0)

  #define STORE(I) do {                                                    \
    if (tid < 512) {                                                       \
      const int trow = tid >> 3, j = tid & 7;                              \
      const int t16 = trow & 15, ts = trow >> 4;                           \
      const float sum = Plds[ts][0][t16][j] + Plds[ts][1][t16][j] +        \
                        Plds[ts][2][t16][j] + Plds[ts][3][t16][j] + bo_j;  \
      outb[(size_t)((I) * TT + trow) * OUTt + j] = 1.f / (1.f + __expf(-sum)); \
    }                                                                      \
  } while (0)

  // ---------------- prologue ----------------
  float4 PA0, PA1, PB0, PB1;
  ISSUE(0, PA0, PA1);
  ISSUE(1, PB0, PB1);
  STAGE(0, PA0, PA1);                 // tile 0 -> Xb[0]
  STAGE(1, PB0, PB1);                 // tile 1 -> Xb[1]
  ISSUE(2, PA0, PA1);                 // tile 2 in flight
  __syncthreads();
  {
    f32x4 d0[2][2];
    #pragma unroll
    for (int th = 0; th < 2; ++th)
      #pragma unroll
      for (int nh = 0; nh < 2; ++nh) d0[th][nh] = f32x4{0.f, 0.f, 0.f, 0.f};
    GEMM(0, d0);                      // tile 0
    WRITEDF(d0);
  }
  __syncthreads();

  // ---------------- main loop (even/odd pair so P regs index statically) ----
  #define ITER(I, PW0, PW1, PI0, PI1) do {                                 \
    if ((I) + 3 < NTILE) ISSUE((I) + 3, PI0, PI1);                         \
    f32x4 dacc[2][2];                                                      \
    _Pragma("unroll")                                                      \
    for (int th = 0; th < 2; ++th)                                         \
      _Pragma("unroll")                                                    \
      for (int nh = 0; nh < 2; ++nh) dacc[th][nh] = f32x4{0.f,0.f,0.f,0.f};\
    if ((I) + 1 < NTILE) GEMM(((I) + 1) & 1, dacc);                        \
    SCAN();                                                                \
    __syncthreads();  /* B1: Df consumed, Mb ready, Xb[(I+1)&1] consumed */ \
    if ((I) + 1 < NTILE) WRITEDF(dacc);                                    \
    if ((I) + 2 < NTILE) STAGE((I) & 1, PW0, PW1);                         \
    PROJ();                                                                \
    __syncthreads();  /* B2: Df/Xb ready for next iter, Plds ready */      \
    STORE(I);                                                              \
  } while (0)

  for (int ii = 0; ii < NTILE / 2; ++ii) {
    ITER(2 * ii,     PA0, PA1, PB0, PB1);   // waits tile 2ii+2 (PA), issues 2ii+3 (PB)
    ITER(2 * ii + 1, PB0, PB1, PA0, PA1);   // waits tile 2ii+3 (PB), issues 2ii+4 (PA)
  }

  #undef ISSUE
  #undef STAGE
  #undef GEMM
  #undef WRITEDF
  #undef SCAN
  #undef PROJ
  #undef STORE
  #undef ITER
}

extern "C" void kernel_launch(void* const* d_in, const int* in_sizes, int n_in,
                              void* d_out, int out_size, void* d_ws, size_t ws_size,
                              hipStream_t stream) {
  const float* x     = (const float*)d_in[0];
  const float* Wb    = (const float*)d_in[1];
  const float* bb    = (const float*)d_in[2];
  const float* Wo    = (const float*)d_in[3];
  const float* bo    = (const float*)d_in[4];
  const float* tau_m = (const float*)d_in[5];
  const float* tau_n = (const float*)d_in[6];
  float* out = (float*)d_out;

  sfnn_fused<<<dim3(256), dim3(1024), 0, stream>>>(x, Wb, bb, Wo, bo, tau_m, tau_n, out);
}